// Round 9
// baseline (319.036 us; speedup 1.0000x reference)
//
#include <hip/hip_runtime.h>
#include <hip/hip_bf16.h>

// ---------------------------------------------------------------------------
// GINE GNN. Features: f16 plane (self/MLP) + fp8-e4m3 shadow plane gathered
// per-edge (halves per-XCD L2-fill). CSR: single-pass bucket binning +
// per-bucket sort with register staging and direct global pairs writes.
// r9: r7's agg+MLP fusion RETRIED with r8's gather layout (wave = 4 nodes x
// 16 lanes, 16-deep gather pipeline, no cross-lane reduce): aggregation
// results go straight into MFMA-swizzled LDS bufA, deleting the P1 global
// round-trip (51MB x 3 layers) and 3 dispatches. r7 failed only because its
// gather had 4-deep MLP (1.5TB/s); r8 fixed that (agg ~25us/layer).
// Lessons: r2 = cross-XCD fine-grain scatter kills via write-amp/latency;
// r4 = never trade register accumulation for LDS atomics; r5/r6 = CSR build
// latency-bound, frozen at ~128us; r8 = gather MLP depth is the agg lever.
// ---------------------------------------------------------------------------

#define HID 128
#define NCLS 3
#define EPB 8192          // edges per binning block
#define BSHIFT 6          // bucket = dst >> 6 (64 nodes/bucket)
#define BNODES 64
#define ECAP 2040         // slots per bucket (mean padded ~1690, +11 sigma)

typedef _Float16 f16;
typedef f16 f16x2 __attribute__((ext_vector_type(2)));
typedef f16 f16x8 __attribute__((ext_vector_type(8)));
typedef float f32x2 __attribute__((ext_vector_type(2)));
typedef float f32x4 __attribute__((ext_vector_type(4)));
typedef unsigned short ushort;

__device__ __forceinline__ float bcf(int v) {
    return __builtin_bit_cast(float, v);
}
__device__ __forceinline__ float f16bits2f(ushort u) {
    return (float)__builtin_bit_cast(f16, u);
}

// ---- CSR build: ONE pass count+reserve(line-aligned)+place ----------------
// ebuf slot: x = src | (dstlocal<<24)  (never -1; -1 = padding sentinel)
//            y = (attr_f16<<16) | msg0_f16

__global__ __launch_bounds__(1024) void k_bin2(const int* __restrict__ src,
                                               const int* __restrict__ dst,
                                               const float* __restrict__ eattr,
                                               const float* __restrict__ x,
                                               int* __restrict__ cursor,
                                               int2* __restrict__ ebuf,
                                               int E, int NB) {
    __shared__ int lh[2048];
    __shared__ int lbase[2048];
    __shared__ int lrsv[2048];
    int t = threadIdx.x;
    for (int b = t; b < NB; b += 1024) lh[b] = 0;
    __syncthreads();
    int base = blockIdx.x * EPB;
    int myd[8];
    #pragma unroll
    for (int j = 0; j < 8; ++j) {
        int e = base + j * 1024 + t;
        myd[j] = (e < E) ? dst[e] : -1;
        if (myd[j] >= 0) atomicAdd(&lh[myd[j] >> BSHIFT], 1);
    }
    __syncthreads();
    for (int b = t; b < NB; b += 1024) {
        int c = lh[b];
        int cp = (c + 7) & ~7;           // 64B-line-aligned reservation
        lrsv[b] = cp;
        lbase[b] = (cp > 0) ? (b * ECAP + atomicAdd(&cursor[b], cp)) : 0;
        lh[b] = 0;
    }
    __syncthreads();
    #pragma unroll
    for (int j = 0; j < 8; ++j) {
        if (myd[j] >= 0) {
            int e = base + j * 1024 + t;
            int b = myd[j] >> BSHIFT;
            int s = src[e];
            float at = eattr[e];
            float msg = fmaxf(x[s] + at, 0.f);   // layer-0 message, hidden
            unsigned a16 = __builtin_bit_cast(ushort, (f16)at);
            unsigned m16 = __builtin_bit_cast(ushort, (f16)msg);
            int r = atomicAdd(&lh[b], 1);
            int pos = lbase[b] + r;
            if (pos < (b + 1) * ECAP)          // overflow guard (never hits)
                ebuf[pos] = make_int2(s | ((myd[j] & (BNODES - 1)) << 24),
                                      (int)((a16 << 16) | m16));
        }
    }
    __syncthreads();
    // sentinel-fill this block's padding (<=7 per bucket, own lines)
    for (int b = t; b < NB; b += 1024) {
        int c = lh[b], cp = lrsv[b];
        int p0 = lbase[b] + c;
        int pe = lbase[b] + cp;
        int cap = (b + 1) * ECAP;
        if (pe > cap) pe = cap;
        for (int pos = p0; pos < pe; ++pos)
            ebuf[pos] = make_int2(-1, 0);
    }
}

// ---- prep: blocks 0..13 = W prefragmentation (f16 per-lane MFMA layout);
// block 14 = exclusive scan of bucket totals (2 elems/thread, NB<=2048).

__global__ __launch_bounds__(1024) void k_prep(const float* __restrict__ W2_0,
                                               const float* __restrict__ W1_s,
                                               const float* __restrict__ W2_s,
                                               f16* __restrict__ Wf,
                                               const int* __restrict__ cursor,
                                               int* __restrict__ bbase, int NB) {
    int t = threadIdx.x;
    if (blockIdx.x < 14) {
        int id = blockIdx.x * 1024 + t;         // [0, 14336)
        int lane = id & 63;
        int w    = (id >> 6) & 3;
        int nf   = (id >> 8) & 1;
        int kk   = (id >> 9) & 3;
        int g    = id >> 11;
        const float* W = (g == 0) ? W2_0
                       : ((g & 1) ? W1_s + (size_t)((g - 1) >> 1) * HID * HID
                                  : W2_s + (size_t)((g - 2) >> 1) * HID * HID);
        int col = w * 32 + nf * 16 + (lane & 15);
        int k0  = kk * 32 + (lane >> 4) * 8;
        f16x8 hi;
        #pragma unroll
        for (int j = 0; j < 8; ++j)
            hi[j] = (f16)W[(k0 + j) * HID + col];
        size_t o = ((((size_t)g * 4 + kk) * 2 + nf) * 4 + w) * 512 +
                   (size_t)lane * 8;
        *(f16x8*)&Wf[o] = hi;
    } else {
        __shared__ int sd[1024];
        int i0 = 2 * t, i1 = 2 * t + 1;
        int a = (i0 < NB) ? min(cursor[i0], ECAP) : 0;
        int b = (i1 < NB) ? min(cursor[i1], ECAP) : 0;
        int s = a + b;
        sd[t] = s;
        __syncthreads();
        #pragma unroll
        for (int o = 1; o < 1024; o <<= 1) {
            int add = (t >= o) ? sd[t - o] : 0;
            __syncthreads();
            sd[t] += add;
            __syncthreads();
        }
        int excl = sd[t] - s;                  // exclusive sum of pair-sums
        if (i0 < NB) bbase[i0] = excl;
        if (i1 < NB) bbase[i1] = excl + a;
        if (t == 1023) bbase[NB] = sd[1023];
    }
}

// per-bucket (64 nodes): global read into REGISTERS (<=8 slots per thread,
// statically unrolled); skip sentinels; count via LDS atomics; scan of 64
// counters by wave 0 via shfl; place DIRECTLY to global pairs
// (block-exclusive region -> L2-absorbed, written back once).
// pairs.x = src*128 byte offset (fp8 plane); pairs.y = f32 attr bits.
__global__ __launch_bounds__(256, 8) void k_fill2(const int2* __restrict__ ebuf,
                                               const int* __restrict__ btot,
                                               const int* __restrict__ bbase,
                                               const float* __restrict__ x,
                                               const int* __restrict__ batch,
                                               int2* __restrict__ meta,
                                               int2* __restrict__ pairs,
                                               float* __restrict__ hin0,
                                               int* __restrict__ gcount,
                                               int* __restrict__ gstart,
                                               int N) {
    __shared__ int lcnt[BNODES];
    __shared__ int lofs[BNODES];
    __shared__ float satom[BNODES];
    int b = blockIdx.x, t = threadIdx.x;
    int estart = b * ECAP;
    int cnt = min(btot[b], ECAP);
    int pstart = bbase[b];
    int nb0 = b << BSHIFT;
    if (t < BNODES) {
        lcnt[t] = 0;
        satom[t] = 0.f;
        int node = nb0 + t;                    // graph-segment prep
        if (node < N) {
            int gb = batch[node];
            atomicAdd(&gcount[gb], 1);
            if (node == 0 || batch[node - 1] != gb) gstart[gb] = node;
        }
    }
    __syncthreads();
    // load slots into registers: 8 independent loads in flight, then count
    int2 myv[8];
    #pragma unroll
    for (int j = 0; j < 8; ++j) {
        int i = j * 256 + t;
        if (i < cnt) myv[j] = ebuf[estart + i];
    }
    #pragma unroll
    for (int j = 0; j < 8; ++j) {
        int i = j * 256 + t;
        if (i < cnt && myv[j].x != -1)
            atomicAdd(&lcnt[((unsigned)myv[j].x) >> 24], 1);
    }
    __syncthreads();
    // wave 0 scans the 64 counters via shfl (1 elem/lane, no barriers)
    if (t < 64) {
        int a = lcnt[t];
        int sa = a;
        #pragma unroll
        for (int o = 1; o < 64; o <<= 1) {
            int v = __shfl_up(sa, o);
            if (t >= o) sa += v;
        }
        int ea = sa - a;                      // exclusive offset
        lofs[t] = ea;
        lcnt[t] = 0;
        int n0 = nb0 + t;
        if (n0 < N) meta[n0] = make_int2(pstart + ea, a);
    }
    __syncthreads();
    // place: direct global write (region is block-exclusive, L2-resident);
    // satom adds the precomputed f16 message
    #pragma unroll
    for (int j = 0; j < 8; ++j) {
        int i = j * 256 + t;
        if (i < cnt) {
            int2 v = myv[j];
            if (v.x != -1) {
                int ld = ((unsigned)v.x) >> 24;
                int srcid = v.x & 0x00FFFFFF;
                ushort a16 = (ushort)(((unsigned)v.y) >> 16);
                ushort m16 = (ushort)(v.y & 0xFFFF);
                int r = atomicAdd(&lcnt[ld], 1);
                int pos = lofs[ld] + r;
                pairs[pstart + pos] = make_int2(srcid << 7,
                                     __builtin_bit_cast(int, f16bits2f(a16)));
                atomicAdd(&satom[ld], f16bits2f(m16));
            }
        }
    }
    __syncthreads();
    if (t < BNODES) {
        int node = nb0 + t;
        if (node < N) hin0[node] = x[node] + satom[t];
    }
}

// ---- gather helpers (r8 layout: 16 lanes/node, 16-deep pipeline) ----------

__device__ __forceinline__ void agg_add8(f32x2 acc2[4], uint2 g, float e) {
    f32x2 e2 = {e, e}, z2 = {0.f, 0.f};
    unsigned gw[2] = {g.x, g.y};
    #pragma unroll
    for (int ww = 0; ww < 2; ++ww) {
        f32x2 lo = __builtin_amdgcn_cvt_pk_f32_fp8((int)gw[ww], false);
        f32x2 hi = __builtin_amdgcn_cvt_pk_f32_fp8((int)gw[ww], true);
        lo = __builtin_elementwise_max(lo + e2, z2);
        hi = __builtin_elementwise_max(hi + e2, z2);
        acc2[2 * ww]     += lo;
        acc2[2 * ww + 1] += hi;
    }
}

__device__ __forceinline__ uint2 agg_ld8(const char* __restrict__ hb,
                                         int voff) {
    return *(const uint2*)(hb + (unsigned)voff);
}

// ---- MLP helpers (single-product f16 weights) -----------------------------

__device__ __forceinline__ void load_wfrags1(const f16* __restrict__ Wfg,
                                             int w, int lane,
                                             f16x8 whf[4][2]) {
    #pragma unroll
    for (int kk = 0; kk < 4; ++kk)
        #pragma unroll
        for (int nf = 0; nf < 2; ++nf) {
            size_t o = (((size_t)kk * 2 + nf) * 4 + w) * 512 +
                       (size_t)lane * 8;
            whf[kk][nf] = *(const f16x8*)&Wfg[o];
        }
}

__device__ __forceinline__ void do_gemm1(const f16* Ah,
                                         const f16x8 whf[4][2],
                                         int lane, f32x4 acc[4][2]) {
    int arow = lane & 15, akgrp = lane >> 4;
    #pragma unroll
    for (int kk = 0; kk < 4; ++kk) {
        int chunk = kk * 4 + akgrp;
        f16x8 ah[4];
        #pragma unroll
        for (int mf = 0; mf < 4; ++mf) {
            int r = mf * 16 + arow;
            int swz = chunk ^ (r & 15);
            ah[mf] = *(const f16x8*)&Ah[r * HID + swz * 8];
        }
        #pragma unroll
        for (int mf = 0; mf < 4; ++mf)
            #pragma unroll
            for (int nf = 0; nf < 2; ++nf)
                acc[mf][nf] = __builtin_amdgcn_mfma_f32_16x16x32_f16(
                    ah[mf], whf[kk][nf], acc[mf][nf], 0, 0, 0);
    }
}

// ---- FUSED layer: r8-style gather for 64 nodes -> swizzled LDS, 2-GEMM ----
// reads plane A (hf f16 self + h8 fp8 gather), writes plane B (O + O8).
// Each wave handles rows [w*16, w*16+16) in 4 passes of 4 nodes (g=lane>>4);
// per pass, 16 independent 8B gathers in flight per lane, reg accumulate,
// all 64 lanes convert+store f16x8 into bufA (MFMA swizzle).

__global__ __launch_bounds__(256, 3) void k_aggmlp(
    const unsigned char* __restrict__ h8, const f16* __restrict__ hf,
    const int2* __restrict__ pairs, const int2* __restrict__ meta,
    const f16* __restrict__ Wf1, const float* __restrict__ b1,
    const f16* __restrict__ Wf2, const float* __restrict__ b2,
    f16* __restrict__ O, unsigned char* __restrict__ O8, int w8, int n) {

    __shared__ __align__(16) f16 bufA[64 * HID];   // agg result, then T
    int t = threadIdx.x, w = t >> 6, lane = t & 63;
    int g = lane >> 4, c = lane & 15;
    int wcol = w * 32, fcol = c, kgrp = g;
    int c8 = c * 8, sbase = g * 16;
    int row0 = blockIdx.x * 64;
    const char* hb = (const char*)h8;

    #pragma unroll
    for (int pass = 0; pass < 4; ++pass) {
        int r = w * 16 + pass * 4 + g;
        int node = row0 + r;
        int2 m = make_int2(0, 0);
        if (node < n) m = meta[node];
        int off = m.x, d = m.y;
        f32x2 acc2[4] = {{0.f,0.f},{0.f,0.f},{0.f,0.f},{0.f,0.f}};

        for (int wb = 0; wb < d; wb += 16) {
            int rem = d - wb;
            int mm = rem < 16 ? rem : 16;
            int2 pr = make_int2(0, 0);
            if (c < mm) pr = pairs[off + wb + c];
            uint2 gg[16];
            #pragma unroll
            for (int p = 0; p < 16; ++p) {
                int s = __shfl(pr.x, sbase + p);
                if (p < mm) gg[p] = agg_ld8(hb, s + c8);
            }
            #pragma unroll
            for (int p = 0; p < 16; ++p) {
                if (p < mm) {
                    float e = bcf(__shfl(pr.y, sbase + p));
                    agg_add8(acc2, gg[p], e);
                }
            }
        }

        f16x8 ov = (f16x8)(f16)0.f;
        if (node < n) {
            uint4 sg = *(const uint4*)&hf[(size_t)node * HID + c8];
            unsigned sw[4] = {sg.x, sg.y, sg.z, sg.w};
            #pragma unroll
            for (int ww = 0; ww < 4; ++ww) {
                f16x2 s = __builtin_bit_cast(f16x2, sw[ww]);
                ov[2 * ww]     = (f16)((float)s[0] + acc2[ww].x);
                ov[2 * ww + 1] = (f16)((float)s[1] + acc2[ww].y);
            }
        }
        int swz = c ^ (r & 15);                 // MFMA LDS swizzle
        *(f16x8*)&bufA[r * HID + swz * 8] = ov;
    }

    f32x4 acc[4][2];
    {
        f16x8 whf[4][2];
        load_wfrags1(Wf1, w, lane, whf);
        float bv0 = b1[wcol + fcol], bv1 = b1[wcol + 16 + fcol];
        __syncthreads();                    // bufA fully written
        #pragma unroll
        for (int mf = 0; mf < 4; ++mf)
            #pragma unroll
            for (int nf = 0; nf < 2; ++nf)
                acc[mf][nf] = (f32x4)(0.f);
        do_gemm1(bufA, whf, lane, acc);
        __syncthreads();   // all A reads done before T overwrites
        #pragma unroll
        for (int mf = 0; mf < 4; ++mf)
            #pragma unroll
            for (int nf = 0; nf < 2; ++nf) {
                int cc = wcol + nf * 16 + fcol;
                float bb = nf ? bv1 : bv0;
                #pragma unroll
                for (int j = 0; j < 4; ++j) {
                    int r = mf * 16 + kgrp * 4 + j;
                    float v = fmaxf(acc[mf][nf][j] + bb, 0.f);
                    int addr = r * HID + (((cc >> 3) ^ (r & 15)) << 3) + (cc & 7);
                    bufA[addr] = (f16)v;
                }
            }
    }
    {
        f16x8 whf[4][2];
        load_wfrags1(Wf2, w, lane, whf);
        float bv0 = b2[wcol + fcol], bv1 = b2[wcol + 16 + fcol];
        __syncthreads();
        #pragma unroll
        for (int mf = 0; mf < 4; ++mf)
            #pragma unroll
            for (int nf = 0; nf < 2; ++nf)
                acc[mf][nf] = (f32x4)(0.f);
        do_gemm1(bufA, whf, lane, acc);

        #pragma unroll
        for (int mf = 0; mf < 4; ++mf)
            #pragma unroll
            for (int nf = 0; nf < 2; ++nf) {
                int cc = wcol + nf * 16 + fcol;
                float bb = nf ? bv1 : bv0;
                #pragma unroll
                for (int j = 0; j < 4; ++j) {
                    int r = row0 + mf * 16 + kgrp * 4 + j;
                    if (r < n) {
                        float v = fmaxf(acc[mf][nf][j] + bb, 0.f);
                        O[(size_t)r * HID + cc] = (f16)v;
                        if (w8) {
                            int pk = __builtin_amdgcn_cvt_pk_fp8_f32(
                                v, v, 0, false);
                            O8[(size_t)r * HID + cc] =
                                (unsigned char)(pk & 0xFF);
                        }
                    }
                }
            }
    }
}

// ---- layer-0 MLP (rank-1 expansion fused) ---------------------------------

__global__ __launch_bounds__(256, 3) void k_mlp0(
    const float* __restrict__ r1x, const float* __restrict__ r1w,
    const float* __restrict__ r1b,
    const f16* __restrict__ Wf2, const float* __restrict__ b2,
    f16* __restrict__ O, unsigned char* __restrict__ O8, int n) {

    __shared__ __align__(16) f16 bufA[64 * HID];
    int t = threadIdx.x, w = t >> 6, lane = t & 63;
    int wcol = w * 32, fcol = lane & 15, kgrp = lane >> 4;
    int row0 = blockIdx.x * 64;

    #pragma unroll
    for (int rep = 0; rep < 4; ++rep) {
        int task = rep * 256 + t;
        int r = task >> 4, ch = task & 15;
        int gr = min(row0 + r, n - 1);
        int swz = ch ^ (r & 15);
        float xv = r1x[gr];
        f16x8 hi;
        #pragma unroll
        for (int j = 0; j < 8; ++j)
            hi[j] = (f16)fmaxf(xv * r1w[ch * 8 + j] + r1b[ch * 8 + j], 0.f);
        *(f16x8*)&bufA[r * HID + swz * 8] = hi;
    }

    f16x8 whf[4][2];
    load_wfrags1(Wf2, w, lane, whf);
    float bv0 = b2[wcol + fcol], bv1 = b2[wcol + 16 + fcol];
    __syncthreads();
    f32x4 acc[4][2];
    #pragma unroll
    for (int mf = 0; mf < 4; ++mf)
        #pragma unroll
        for (int nf = 0; nf < 2; ++nf)
            acc[mf][nf] = (f32x4)(0.f);
    do_gemm1(bufA, whf, lane, acc);

    #pragma unroll
    for (int mf = 0; mf < 4; ++mf)
        #pragma unroll
        for (int nf = 0; nf < 2; ++nf) {
            int cc = wcol + nf * 16 + fcol;
            float bb = nf ? bv1 : bv0;
            #pragma unroll
            for (int j = 0; j < 4; ++j) {
                int r = row0 + mf * 16 + kgrp * 4 + j;
                if (r < n) {
                    float v = fmaxf(acc[mf][nf][j] + bb, 0.f);
                    O[(size_t)r * HID + cc] = (f16)v;
                    int pk = __builtin_amdgcn_cvt_pk_fp8_f32(v, v, 0, false);
                    O8[(size_t)r * HID + cc] = (unsigned char)(pk & 0xFF);
                }
            }
        }
}

// ---- mean pool + head: 256 threads, 4 rows in flight, f16x2 loads ---------

__global__ __launch_bounds__(256) void k_head(const f16* __restrict__ h,
                                              const int* __restrict__ gstart,
                                              const int* __restrict__ gcount,
                                              const float* __restrict__ Wc,
                                              const float* __restrict__ bc,
                                              float* __restrict__ out, int G) {
    __shared__ float2 red[4][64];
    __shared__ float pl[HID];
    int g = blockIdx.x, t = threadIdx.x;
    int rr = t >> 6, cc = t & 63;
    int st = gstart[g], c = gcount[g];
    float2 acc = make_float2(0.f, 0.f);
    for (int i = rr; i < c; i += 4) {
        unsigned u = *(const unsigned*)&h[(size_t)(st + i) * HID + cc * 2];
        f16x2 v = __builtin_bit_cast(f16x2, u);
        acc.x += (float)v[0];
        acc.y += (float)v[1];
    }
    red[rr][cc] = acc;
    __syncthreads();
    if (rr == 0) {
        #pragma unroll
        for (int k = 1; k < 4; ++k) {
            acc.x += red[k][cc].x;
            acc.y += red[k][cc].y;
        }
        float inv = 1.f / fmaxf((float)c, 1.f);
        pl[cc * 2]     = acc.x * inv;
        pl[cc * 2 + 1] = acc.y * inv;
    }
    __syncthreads();
    if (t < NCLS) {
        float o = bc[t];
        for (int k = 0; k < HID; ++k) o += pl[k] * Wc[k * NCLS + t];
        out[g * NCLS + t] = o;
    }
}

// ---------------------------------------------------------------------------

static inline size_t alignup(size_t x, size_t a) { return (x + a - 1) & ~(a - 1); }

extern "C" void kernel_launch(void* const* d_in, const int* in_sizes, int n_in,
                              void* d_out, int out_size, void* d_ws, size_t ws_size,
                              hipStream_t stream) {
    const float* x      = (const float*)d_in[0];
    const int*   ei     = (const int*)d_in[1];
    const float* eattr  = (const float*)d_in[2];
    const int*   batch  = (const int*)d_in[3];
    const float* W1_0   = (const float*)d_in[4];
    const float* b1_0   = (const float*)d_in[5];
    const float* W2_0   = (const float*)d_in[6];
    const float* b2_0   = (const float*)d_in[7];
    const float* W1_s   = (const float*)d_in[8];
    const float* b1_s   = (const float*)d_in[9];
    const float* W2_s   = (const float*)d_in[10];
    const float* b2_s   = (const float*)d_in[11];
    const float* Wc     = (const float*)d_in[12];
    const float* bc     = (const float*)d_in[13];

    const int N = in_sizes[0];          // 100000
    const int E = in_sizes[2];          // 1600000
    const int G = out_size / NCLS;      // 1000
    const int* srcI = ei;
    const int* dstI = ei + E;

    const int NB = (N + BNODES - 1) >> BSHIFT;          // 1563 buckets
    const int NBLK = (E + EPB - 1) / EPB;               // 196 binning blocks

    char* p = (char*)d_ws;
    size_t off = 0;
    size_t gcount_off = off;         off = alignup(off + (size_t)G * 4, 256);
    size_t gstart_off = off;         off = alignup(off + (size_t)G * 4, 256);
    size_t cursor_off = off;         off = alignup(off + 2048 * 4, 256);
    size_t zero_bytes = off;
    size_t meta_off = off;           off = alignup(off + (size_t)N * 8, 256);
    size_t bbase_off = off;          off = alignup(off + 2049 * 4, 256);
    size_t hin0_off = off;           off = alignup(off + (size_t)N * 4, 256);
    size_t wf_off = off;             off = alignup(off + 7 * 16384 * 2, 256);
    size_t pairs_off = off;          off = alignup(off + (size_t)NB * ECAP * 8, 256);
    size_t p0f_off = off;            off = alignup(off + (size_t)N * HID * 2, 256);
    size_t p0q_off = off;            off = alignup(off + (size_t)N * HID, 256);
    size_t p1f_off = off;            off = alignup(off + (size_t)N * HID * 2, 256);
    size_t p1q_off = off;            off = alignup(off + (size_t)N * HID, 256);

    int*    gcount  = (int*)(p + gcount_off);
    int*    gstart  = (int*)(p + gstart_off);
    int*    cursor  = (int*)(p + cursor_off);
    int2*   meta    = (int2*)(p + meta_off);
    int*    bbase   = (int*)(p + bbase_off);
    float*  hin0    = (float*)(p + hin0_off);
    f16*    Wf      = (f16*)(p + wf_off);
    int2*   pairs   = (int2*)(p + pairs_off);
    f16*    P0f     = (f16*)(p + p0f_off);
    unsigned char* P0q = (unsigned char*)(p + p0q_off);
    f16*    P1f     = (f16*)(p + p1f_off);
    unsigned char* P1q = (unsigned char*)(p + p1q_off);
    // ebuf aliases P1f (dead until layer-1's k_aggmlp writes it; consumed
    // by k_fill2 before that): NB*ECAP*8 = 25.51MB <= N*HID*2B = 25.6MB
    int2*   ebuf    = (int2*)(p + p1f_off);

    hipMemsetAsync(d_ws, 0, zero_bytes, stream);

    int gblk = (N + 63) / 64;           // == NB

    k_bin2<<<NBLK, 1024, 0, stream>>>(srcI, dstI, eattr, x, cursor, ebuf,
                                      E, NB);
    k_prep<<<15, 1024, 0, stream>>>(W2_0, W1_s, W2_s, Wf, cursor, bbase, NB);
    k_fill2<<<NB, 256, 0, stream>>>(ebuf, cursor, bbase, x, batch, meta,
                                    pairs, hin0, gcount, gstart, N);

    // Wf plane bases: g=0 -> W2_0; g=1+2l -> W1_s[l]; g=2+2l -> W2_s[l]
    #define WFG(g) (Wf + (size_t)(g) * 16384)

    // layer 0: rank1-expand + GEMM(W2_0) -> plane A (P0f + P0q shadow)
    k_mlp0<<<gblk, 256, 0, stream>>>(hin0, W1_0, b1_0, WFG(0), b2_0,
                                     P0f, P0q, N);

    // layers 1..3 fused agg+MLP, ping-pong planes: A->B->A->B
    k_aggmlp<<<gblk, 256, 0, stream>>>(P0q, P0f, pairs, meta,
                                       WFG(1), b1_s, WFG(2), b2_s,
                                       P1f, P1q, 1, N);
    k_aggmlp<<<gblk, 256, 0, stream>>>(P1q, P1f, pairs, meta,
                                       WFG(3), b1_s + HID, WFG(4), b2_s + HID,
                                       P0f, P0q, 1, N);
    k_aggmlp<<<gblk, 256, 0, stream>>>(P0q, P0f, pairs, meta,
                                       WFG(5), b1_s + 2 * HID,
                                       WFG(6), b2_s + 2 * HID,
                                       P1f, P1q, 0, N);

    k_head<<<G, 256, 0, stream>>>(P1f, gstart, gcount, Wc, bc,
                                  (float*)d_out, G);
}

// Round 10
// 308.592 us; speedup vs baseline: 1.0338x; 1.0338x over previous
//
#include <hip/hip_runtime.h>
#include <hip/hip_bf16.h>

// ---------------------------------------------------------------------------
// GINE GNN. Features: f16 plane (self/MLP) + fp8-e4m3 shadow plane gathered
// by k_agg (r8 layout: wave = 4 nodes x 16 lanes, 16-deep gather pipeline,
// no cross-lane reduce -- agg is near its ~20us/layer random-gather floor).
// CSR: single-pass bucket binning + per-bucket sort, register staging,
// direct global pairs writes. r10: binning bucket coarsened to 256 nodes
// (BSHIFT 8, NB=391): mean edges per (block,bucket) 5.2->21, so the 8-slot
// line-aligned reservations now fill ~77% of 64B lines fully -- attacks
// k_bin2's measured write-path bound (WRITE 58MB vs 12.8 logical = each
// scattered 8B store costs a line; 102MB/1.5TB/s = the 66us).
// Lessons: r2 = cross-XCD fine-grain scatter kills; r4 = never trade reg
// accumulation for LDS atomics / per-wave-serial edges; r8 = gather MLP
// depth is the agg lever; r9 = agg+MLP fusion is net-neutral (serializes
// gather behind GEMM, cancels the P1 saving).
// ---------------------------------------------------------------------------

#define HID 128
#define NCLS 3
#define EPB 8192          // edges per binning block
#define BSHIFT 8          // bucket = dst >> 8 (256 nodes/bucket)
#define BNODES 256
#define ECAP 5504         // slots per bucket (mean padded ~4780, +10 sigma)

typedef _Float16 f16;
typedef f16 f16x2 __attribute__((ext_vector_type(2)));
typedef f16 f16x8 __attribute__((ext_vector_type(8)));
typedef float f32x2 __attribute__((ext_vector_type(2)));
typedef float f32x4 __attribute__((ext_vector_type(4)));
typedef unsigned short ushort;

__device__ __forceinline__ float bcf(int v) {
    return __builtin_bit_cast(float, v);
}
__device__ __forceinline__ float f16bits2f(ushort u) {
    return (float)__builtin_bit_cast(f16, u);
}

// ---- CSR build: ONE pass count+reserve(line-aligned)+place ----------------
// ebuf slot: x = src | (dstlocal<<24)  (sentinel -1 impossible: src<2^24-1)
//            y = (attr_f16<<16) | msg0_f16

__global__ __launch_bounds__(1024) void k_bin2(const int* __restrict__ src,
                                               const int* __restrict__ dst,
                                               const float* __restrict__ eattr,
                                               const float* __restrict__ x,
                                               int* __restrict__ cursor,
                                               int2* __restrict__ ebuf,
                                               int E, int NB) {
    __shared__ int lh[512];
    __shared__ int lbase[512];
    __shared__ int lrsv[512];
    int t = threadIdx.x;
    if (t < NB) lh[t] = 0;
    __syncthreads();
    int base = blockIdx.x * EPB;
    int myd[8];
    #pragma unroll
    for (int j = 0; j < 8; ++j) {
        int e = base + j * 1024 + t;
        myd[j] = (e < E) ? dst[e] : -1;
        if (myd[j] >= 0) atomicAdd(&lh[myd[j] >> BSHIFT], 1);
    }
    __syncthreads();
    if (t < NB) {
        int c = lh[t];
        int cp = (c + 7) & ~7;           // 64B-line-aligned reservation
        lrsv[t] = cp;
        lbase[t] = (cp > 0) ? (t * ECAP + atomicAdd(&cursor[t], cp)) : 0;
        lh[t] = 0;
    }
    __syncthreads();
    #pragma unroll
    for (int j = 0; j < 8; ++j) {
        if (myd[j] >= 0) {
            int e = base + j * 1024 + t;
            int b = myd[j] >> BSHIFT;
            int s = src[e];
            float at = eattr[e];
            float msg = fmaxf(x[s] + at, 0.f);   // layer-0 message, hidden
            unsigned a16 = __builtin_bit_cast(ushort, (f16)at);
            unsigned m16 = __builtin_bit_cast(ushort, (f16)msg);
            int r = atomicAdd(&lh[b], 1);
            int pos = lbase[b] + r;
            if (pos < (b + 1) * ECAP)          // overflow guard (never hits)
                ebuf[pos] = make_int2(s | ((myd[j] & (BNODES - 1)) << 24),
                                      (int)((a16 << 16) | m16));
        }
    }
    __syncthreads();
    // sentinel-fill this block's padding (<=7 per bucket, own lines)
    if (t < NB) {
        int c = lh[t], cp = lrsv[t];
        int p0 = lbase[t] + c;
        int pe = lbase[t] + cp;
        int cap = (t + 1) * ECAP;
        if (pe > cap) pe = cap;
        for (int pos = p0; pos < pe; ++pos)
            ebuf[pos] = make_int2(-1, 0);
    }
}

// ---- prep: blocks 0..13 = W prefragmentation (f16 per-lane MFMA layout);
// block 14 = exclusive scan of bucket totals (NB<=1024).

__global__ __launch_bounds__(1024) void k_prep(const float* __restrict__ W2_0,
                                               const float* __restrict__ W1_s,
                                               const float* __restrict__ W2_s,
                                               f16* __restrict__ Wf,
                                               const int* __restrict__ cursor,
                                               int* __restrict__ bbase, int NB) {
    int t = threadIdx.x;
    if (blockIdx.x < 14) {
        int id = blockIdx.x * 1024 + t;         // [0, 14336)
        int lane = id & 63;
        int w    = (id >> 6) & 3;
        int nf   = (id >> 8) & 1;
        int kk   = (id >> 9) & 3;
        int g    = id >> 11;
        const float* W = (g == 0) ? W2_0
                       : ((g & 1) ? W1_s + (size_t)((g - 1) >> 1) * HID * HID
                                  : W2_s + (size_t)((g - 2) >> 1) * HID * HID);
        int col = w * 32 + nf * 16 + (lane & 15);
        int k0  = kk * 32 + (lane >> 4) * 8;
        f16x8 hi;
        #pragma unroll
        for (int j = 0; j < 8; ++j)
            hi[j] = (f16)W[(k0 + j) * HID + col];
        size_t o = ((((size_t)g * 4 + kk) * 2 + nf) * 4 + w) * 512 +
                   (size_t)lane * 8;
        *(f16x8*)&Wf[o] = hi;
    } else {
        __shared__ int sd[1024];
        int v = (t < NB) ? min(cursor[t], ECAP) : 0;
        sd[t] = v;
        __syncthreads();
        #pragma unroll
        for (int o = 1; o < 1024; o <<= 1) {
            int add = (t >= o) ? sd[t - o] : 0;
            __syncthreads();
            sd[t] += add;
            __syncthreads();
        }
        if (t < NB) bbase[t] = sd[t] - v;
        if (t == 1023) bbase[NB] = sd[1023];
    }
}

// per-bucket (256 nodes): global read into REGISTERS (<=11 slots per thread,
// statically unrolled); skip sentinels; count via LDS atomics; scan of 256
// counters by wave 0 via shfl (4 counters/lane); place DIRECTLY to global
// pairs (block-exclusive region -> L2-absorbed, written back once).
// pairs.x = src*128 byte offset (fp8 plane); pairs.y = f32 attr bits.
__global__ __launch_bounds__(512, 8) void k_fill2(const int2* __restrict__ ebuf,
                                               const int* __restrict__ btot,
                                               const int* __restrict__ bbase,
                                               const float* __restrict__ x,
                                               const int* __restrict__ batch,
                                               int2* __restrict__ meta,
                                               int2* __restrict__ pairs,
                                               float* __restrict__ hin0,
                                               int* __restrict__ gcount,
                                               int* __restrict__ gstart,
                                               int N) {
    __shared__ int lcnt[BNODES];
    __shared__ int lofs[BNODES];
    __shared__ float satom[BNODES];
    int b = blockIdx.x, t = threadIdx.x;
    int estart = b * ECAP;
    int cnt = min(btot[b], ECAP);
    int pstart = bbase[b];
    int nb0 = b << BSHIFT;
    if (t < BNODES) {
        lcnt[t] = 0;
        satom[t] = 0.f;
        int node = nb0 + t;                    // graph-segment prep
        if (node < N) {
            int gb = batch[node];
            atomicAdd(&gcount[gb], 1);
            if (node == 0 || batch[node - 1] != gb) gstart[gb] = node;
        }
    }
    __syncthreads();
    // load slots into registers: 11 independent loads in flight, then count
    int2 myv[11];
    #pragma unroll
    for (int j = 0; j < 11; ++j) {
        int i = j * 512 + t;
        if (i < cnt) myv[j] = ebuf[estart + i];
    }
    #pragma unroll
    for (int j = 0; j < 11; ++j) {
        int i = j * 512 + t;
        if (i < cnt && myv[j].x != -1)
            atomicAdd(&lcnt[((unsigned)myv[j].x) >> 24], 1);
    }
    __syncthreads();
    // wave 0 scans the 256 counters via shfl (4 counters/lane)
    if (t < 64) {
        int c0 = lcnt[4 * t], c1 = lcnt[4 * t + 1];
        int c2 = lcnt[4 * t + 2], c3 = lcnt[4 * t + 3];
        int s = c0 + c1 + c2 + c3;
        int sa = s;
        #pragma unroll
        for (int o = 1; o < 64; o <<= 1) {
            int v = __shfl_up(sa, o);
            if (t >= o) sa += v;
        }
        int e0 = sa - s;                      // exclusive lane base
        int e1 = e0 + c0, e2 = e1 + c1, e3 = e2 + c2;
        lofs[4 * t] = e0; lofs[4 * t + 1] = e1;
        lofs[4 * t + 2] = e2; lofs[4 * t + 3] = e3;
        lcnt[4 * t] = 0; lcnt[4 * t + 1] = 0;
        lcnt[4 * t + 2] = 0; lcnt[4 * t + 3] = 0;
        int n0 = nb0 + 4 * t;
        if (n0 < N)     meta[n0]     = make_int2(pstart + e0, c0);
        if (n0 + 1 < N) meta[n0 + 1] = make_int2(pstart + e1, c1);
        if (n0 + 2 < N) meta[n0 + 2] = make_int2(pstart + e2, c2);
        if (n0 + 3 < N) meta[n0 + 3] = make_int2(pstart + e3, c3);
    }
    __syncthreads();
    // place: direct global write (region is block-exclusive, L2-resident);
    // satom adds the precomputed f16 message
    #pragma unroll
    for (int j = 0; j < 11; ++j) {
        int i = j * 512 + t;
        if (i < cnt) {
            int2 v = myv[j];
            if (v.x != -1) {
                int ld = ((unsigned)v.x) >> 24;
                int srcid = v.x & 0x00FFFFFF;
                ushort a16 = (ushort)(((unsigned)v.y) >> 16);
                ushort m16 = (ushort)(v.y & 0xFFFF);
                int r = atomicAdd(&lcnt[ld], 1);
                int pos = lofs[ld] + r;
                pairs[pstart + pos] = make_int2(srcid << 7,
                                     __builtin_bit_cast(int, f16bits2f(a16)));
                atomicAdd(&satom[ld], f16bits2f(m16));
            }
        }
    }
    __syncthreads();
    if (t < BNODES) {
        int node = nb0 + t;
        if (node < N) hin0[node] = x[node] + satom[t];
    }
}

// ---- aggregation: wave = 4 nodes x 16 lanes, 16-deep gather pipeline ------

__device__ __forceinline__ void agg_add8(f32x2 acc2[4], uint2 g, float e) {
    f32x2 e2 = {e, e}, z2 = {0.f, 0.f};
    unsigned gw[2] = {g.x, g.y};
    #pragma unroll
    for (int ww = 0; ww < 2; ++ww) {
        f32x2 lo = __builtin_amdgcn_cvt_pk_f32_fp8((int)gw[ww], false);
        f32x2 hi = __builtin_amdgcn_cvt_pk_f32_fp8((int)gw[ww], true);
        lo = __builtin_elementwise_max(lo + e2, z2);
        hi = __builtin_elementwise_max(hi + e2, z2);
        acc2[2 * ww]     += lo;
        acc2[2 * ww + 1] += hi;
    }
}

__device__ __forceinline__ uint2 agg_ld8(const char* __restrict__ hb,
                                         int voff) {
    return *(const uint2*)(hb + (unsigned)voff);
}

__global__ __launch_bounds__(256, 4) void k_agg(
    const unsigned char* __restrict__ h8,
    const f16* __restrict__ hf,
    const int2* __restrict__ pairs,
    const int2* __restrict__ meta,
    f16* __restrict__ oh, int n) {

    int t = threadIdx.x;
    int w = t >> 6, lane = t & 63;
    int g = lane >> 4, c = lane & 15;
    int node = blockIdx.x * 16 + w * 4 + g;
    int c8 = c * 8;
    int sbase = g * 16;
    const char* hb = (const char*)h8;

    int2 m = make_int2(0, 0);
    if (node < n) m = meta[node];
    int off = m.x, d = m.y;
    f32x2 acc2[4] = {{0.f,0.f},{0.f,0.f},{0.f,0.f},{0.f,0.f}};

    for (int wb = 0; wb < d; wb += 16) {
        int rem = d - wb;
        int mm = rem < 16 ? rem : 16;
        int2 pr = make_int2(0, 0);
        if (c < mm) pr = pairs[off + wb + c];
        uint2 gg[16];
        #pragma unroll
        for (int p = 0; p < 16; ++p) {
            int s = __shfl(pr.x, sbase + p);
            if (p < mm) gg[p] = agg_ld8(hb, s + c8);
        }
        #pragma unroll
        for (int p = 0; p < 16; ++p) {
            if (p < mm) {
                float e = bcf(__shfl(pr.y, sbase + p));
                agg_add8(acc2, gg[p], e);
            }
        }
    }

    if (node < n) {
        uint4 sg = *(const uint4*)&hf[(size_t)node * HID + c8];
        unsigned sw[4] = {sg.x, sg.y, sg.z, sg.w};
        unsigned ow[4];
        #pragma unroll
        for (int ww = 0; ww < 4; ++ww) {
            f16x2 s = __builtin_bit_cast(f16x2, sw[ww]);
            f16x2 o;
            o[0] = (f16)((float)s[0] + acc2[ww].x);
            o[1] = (f16)((float)s[1] + acc2[ww].y);
            ow[ww] = __builtin_bit_cast(unsigned, o);
        }
        uint4 o4;
        o4.x = ow[0]; o4.y = ow[1]; o4.z = ow[2]; o4.w = ow[3];
        *(uint4*)&oh[(size_t)node * HID + c8] = o4;
    }
}

// ---- MLP helpers (single-product f16 weights) -----------------------------

__device__ __forceinline__ void load_wfrags1(const f16* __restrict__ Wfg,
                                             int w, int lane,
                                             f16x8 whf[4][2]) {
    #pragma unroll
    for (int kk = 0; kk < 4; ++kk)
        #pragma unroll
        for (int nf = 0; nf < 2; ++nf) {
            size_t o = (((size_t)kk * 2 + nf) * 4 + w) * 512 +
                       (size_t)lane * 8;
            whf[kk][nf] = *(const f16x8*)&Wfg[o];
        }
}

__device__ __forceinline__ void do_gemm1(const f16* Ah,
                                         const f16x8 whf[4][2],
                                         int lane, f32x4 acc[4][2]) {
    int arow = lane & 15, akgrp = lane >> 4;
    #pragma unroll
    for (int kk = 0; kk < 4; ++kk) {
        int chunk = kk * 4 + akgrp;
        f16x8 ah[4];
        #pragma unroll
        for (int mf = 0; mf < 4; ++mf) {
            int r = mf * 16 + arow;
            int swz = chunk ^ (r & 15);
            ah[mf] = *(const f16x8*)&Ah[r * HID + swz * 8];
        }
        #pragma unroll
        for (int mf = 0; mf < 4; ++mf)
            #pragma unroll
            for (int nf = 0; nf < 2; ++nf)
                acc[mf][nf] = __builtin_amdgcn_mfma_f32_16x16x32_f16(
                    ah[mf], whf[kk][nf], acc[mf][nf], 0, 0, 0);
    }
}

// ---- MLP: O = relu(relu(A@W1+b1)@W2+b2), A f16 plane; fp8 shadow write ----

__global__ __launch_bounds__(256, 3) void k_mlp(
    const f16* __restrict__ A_g,
    const f16* __restrict__ Wf1, const float* __restrict__ b1,
    const f16* __restrict__ Wf2, const float* __restrict__ b2,
    f16* __restrict__ O, unsigned char* __restrict__ O8, int w8, int n) {

    __shared__ __align__(16) f16 bufA[64 * HID];   // A, then T
    int t = threadIdx.x, w = t >> 6, lane = t & 63;
    int wcol = w * 32, fcol = lane & 15, kgrp = lane >> 4;
    int row0 = blockIdx.x * 64;

    #pragma unroll
    for (int rep = 0; rep < 4; ++rep) {
        int task = rep * 256 + t;
        int r = task >> 4, ch = task & 15;
        int gr = min(row0 + r, n - 1);
        int swz = ch ^ (r & 15);
        *(f16x8*)&bufA[r * HID + swz * 8] =
            *(const f16x8*)&A_g[(size_t)gr * HID + ch * 8];
    }

    f32x4 acc[4][2];
    {
        f16x8 whf[4][2];
        load_wfrags1(Wf1, w, lane, whf);
        float bv0 = b1[wcol + fcol], bv1 = b1[wcol + 16 + fcol];
        __syncthreads();
        #pragma unroll
        for (int mf = 0; mf < 4; ++mf)
            #pragma unroll
            for (int nf = 0; nf < 2; ++nf)
                acc[mf][nf] = (f32x4)(0.f);
        do_gemm1(bufA, whf, lane, acc);
        __syncthreads();   // all A reads done before T overwrites
        #pragma unroll
        for (int mf = 0; mf < 4; ++mf)
            #pragma unroll
            for (int nf = 0; nf < 2; ++nf) {
                int cc = wcol + nf * 16 + fcol;
                float bb = nf ? bv1 : bv0;
                #pragma unroll
                for (int j = 0; j < 4; ++j) {
                    int r = mf * 16 + kgrp * 4 + j;
                    float v = fmaxf(acc[mf][nf][j] + bb, 0.f);
                    int addr = r * HID + (((cc >> 3) ^ (r & 15)) << 3) + (cc & 7);
                    bufA[addr] = (f16)v;
                }
            }
    }
    {
        f16x8 whf[4][2];
        load_wfrags1(Wf2, w, lane, whf);
        float bv0 = b2[wcol + fcol], bv1 = b2[wcol + 16 + fcol];
        __syncthreads();
        #pragma unroll
        for (int mf = 0; mf < 4; ++mf)
            #pragma unroll
            for (int nf = 0; nf < 2; ++nf)
                acc[mf][nf] = (f32x4)(0.f);
        do_gemm1(bufA, whf, lane, acc);

        #pragma unroll
        for (int mf = 0; mf < 4; ++mf)
            #pragma unroll
            for (int nf = 0; nf < 2; ++nf) {
                int cc = wcol + nf * 16 + fcol;
                float bb = nf ? bv1 : bv0;
                #pragma unroll
                for (int j = 0; j < 4; ++j) {
                    int r = row0 + mf * 16 + kgrp * 4 + j;
                    if (r < n) {
                        float v = fmaxf(acc[mf][nf][j] + bb, 0.f);
                        O[(size_t)r * HID + cc] = (f16)v;
                        if (w8) {
                            int pk = __builtin_amdgcn_cvt_pk_fp8_f32(
                                v, v, 0, false);
                            O8[(size_t)r * HID + cc] =
                                (unsigned char)(pk & 0xFF);
                        }
                    }
                }
            }
    }
}

// ---- layer-0 MLP (rank-1 expansion fused) ---------------------------------

__global__ __launch_bounds__(256, 3) void k_mlp0(
    const float* __restrict__ r1x, const float* __restrict__ r1w,
    const float* __restrict__ r1b,
    const f16* __restrict__ Wf2, const float* __restrict__ b2,
    f16* __restrict__ O, unsigned char* __restrict__ O8, int n) {

    __shared__ __align__(16) f16 bufA[64 * HID];
    int t = threadIdx.x, w = t >> 6, lane = t & 63;
    int wcol = w * 32, fcol = lane & 15, kgrp = lane >> 4;
    int row0 = blockIdx.x * 64;

    #pragma unroll
    for (int rep = 0; rep < 4; ++rep) {
        int task = rep * 256 + t;
        int r = task >> 4, ch = task & 15;
        int gr = min(row0 + r, n - 1);
        int swz = ch ^ (r & 15);
        float xv = r1x[gr];
        f16x8 hi;
        #pragma unroll
        for (int j = 0; j < 8; ++j)
            hi[j] = (f16)fmaxf(xv * r1w[ch * 8 + j] + r1b[ch * 8 + j], 0.f);
        *(f16x8*)&bufA[r * HID + swz * 8] = hi;
    }

    f16x8 whf[4][2];
    load_wfrags1(Wf2, w, lane, whf);
    float bv0 = b2[wcol + fcol], bv1 = b2[wcol + 16 + fcol];
    __syncthreads();
    f32x4 acc[4][2];
    #pragma unroll
    for (int mf = 0; mf < 4; ++mf)
        #pragma unroll
        for (int nf = 0; nf < 2; ++nf)
            acc[mf][nf] = (f32x4)(0.f);
    do_gemm1(bufA, whf, lane, acc);

    #pragma unroll
    for (int mf = 0; mf < 4; ++mf)
        #pragma unroll
        for (int nf = 0; nf < 2; ++nf) {
            int cc = wcol + nf * 16 + fcol;
            float bb = nf ? bv1 : bv0;
            #pragma unroll
            for (int j = 0; j < 4; ++j) {
                int r = row0 + mf * 16 + kgrp * 4 + j;
                if (r < n) {
                    float v = fmaxf(acc[mf][nf][j] + bb, 0.f);
                    O[(size_t)r * HID + cc] = (f16)v;
                    int pk = __builtin_amdgcn_cvt_pk_fp8_f32(v, v, 0, false);
                    O8[(size_t)r * HID + cc] = (unsigned char)(pk & 0xFF);
                }
            }
        }
}

// ---- mean pool + head: 256 threads, 4 rows in flight, f16x2 loads ---------

__global__ __launch_bounds__(256) void k_head(const f16* __restrict__ h,
                                              const int* __restrict__ gstart,
                                              const int* __restrict__ gcount,
                                              const float* __restrict__ Wc,
                                              const float* __restrict__ bc,
                                              float* __restrict__ out, int G) {
    __shared__ float2 red[4][64];
    __shared__ float pl[HID];
    int g = blockIdx.x, t = threadIdx.x;
    int rr = t >> 6, cc = t & 63;
    int st = gstart[g], c = gcount[g];
    float2 acc = make_float2(0.f, 0.f);
    for (int i = rr; i < c; i += 4) {
        unsigned u = *(const unsigned*)&h[(size_t)(st + i) * HID + cc * 2];
        f16x2 v = __builtin_bit_cast(f16x2, u);
        acc.x += (float)v[0];
        acc.y += (float)v[1];
    }
    red[rr][cc] = acc;
    __syncthreads();
    if (rr == 0) {
        #pragma unroll
        for (int k = 1; k < 4; ++k) {
            acc.x += red[k][cc].x;
            acc.y += red[k][cc].y;
        }
        float inv = 1.f / fmaxf((float)c, 1.f);
        pl[cc * 2]     = acc.x * inv;
        pl[cc * 2 + 1] = acc.y * inv;
    }
    __syncthreads();
    if (t < NCLS) {
        float o = bc[t];
        for (int k = 0; k < HID; ++k) o += pl[k] * Wc[k * NCLS + t];
        out[g * NCLS + t] = o;
    }
}

// ---------------------------------------------------------------------------

static inline size_t alignup(size_t x, size_t a) { return (x + a - 1) & ~(a - 1); }

extern "C" void kernel_launch(void* const* d_in, const int* in_sizes, int n_in,
                              void* d_out, int out_size, void* d_ws, size_t ws_size,
                              hipStream_t stream) {
    const float* x      = (const float*)d_in[0];
    const int*   ei     = (const int*)d_in[1];
    const float* eattr  = (const float*)d_in[2];
    const int*   batch  = (const int*)d_in[3];
    const float* W1_0   = (const float*)d_in[4];
    const float* b1_0   = (const float*)d_in[5];
    const float* W2_0   = (const float*)d_in[6];
    const float* b2_0   = (const float*)d_in[7];
    const float* W1_s   = (const float*)d_in[8];
    const float* b1_s   = (const float*)d_in[9];
    const float* W2_s   = (const float*)d_in[10];
    const float* b2_s   = (const float*)d_in[11];
    const float* Wc     = (const float*)d_in[12];
    const float* bc     = (const float*)d_in[13];

    const int N = in_sizes[0];          // 100000
    const int E = in_sizes[2];          // 1600000
    const int G = out_size / NCLS;      // 1000
    const int* srcI = ei;
    const int* dstI = ei + E;

    const int NB = (N + BNODES - 1) >> BSHIFT;          // 391 buckets
    const int NBLK = (E + EPB - 1) / EPB;               // 196 binning blocks

    char* p = (char*)d_ws;
    size_t off = 0;
    size_t gcount_off = off;         off = alignup(off + (size_t)G * 4, 256);
    size_t gstart_off = off;         off = alignup(off + (size_t)G * 4, 256);
    size_t cursor_off = off;         off = alignup(off + 512 * 4, 256);
    size_t zero_bytes = off;
    size_t meta_off = off;           off = alignup(off + (size_t)N * 8, 256);
    size_t bbase_off = off;          off = alignup(off + 513 * 4, 256);
    size_t hin0_off = off;           off = alignup(off + (size_t)N * 4, 256);
    size_t wf_off = off;             off = alignup(off + 7 * 16384 * 2, 256);
    size_t pairs_off = off;          off = alignup(off + (size_t)NB * ECAP * 8, 256);
    size_t p0_off = off;             off = alignup(off + (size_t)N * HID * 2, 256);
    size_t p8_off = off;             off = alignup(off + (size_t)N * HID, 256);
    size_t p1_off = off;             off = alignup(off + (size_t)N * HID * 2, 256);

    int*    gcount  = (int*)(p + gcount_off);
    int*    gstart  = (int*)(p + gstart_off);
    int*    cursor  = (int*)(p + cursor_off);
    int2*   meta    = (int2*)(p + meta_off);
    int*    bbase   = (int*)(p + bbase_off);
    float*  hin0    = (float*)(p + hin0_off);
    f16*    Wf      = (f16*)(p + wf_off);
    int2*   pairs   = (int2*)(p + pairs_off);
    f16*    P0      = (f16*)(p + p0_off);
    unsigned char* P8 = (unsigned char*)(p + p8_off);
    f16*    P1      = (f16*)(p + p1_off);
    // ebuf aliases P1 (dead until layer-1's k_agg writes P1):
    // NB*ECAP*8B = 391*5504*8 = 17.2MB <= N*HID*2B = 25.6MB
    int2*   ebuf    = (int2*)(p + p1_off);

    hipMemsetAsync(d_ws, 0, zero_bytes, stream);

    int gblk = (N + 63) / 64;
    int abl = (N + 15) / 16;            // k_agg: 16 nodes per 256-thr block

    k_bin2<<<NBLK, 1024, 0, stream>>>(srcI, dstI, eattr, x, cursor, ebuf,
                                      E, NB);
    k_prep<<<15, 1024, 0, stream>>>(W2_0, W1_s, W2_s, Wf, cursor, bbase, NB);
    k_fill2<<<NB, 512, 0, stream>>>(ebuf, cursor, bbase, x, batch, meta,
                                    pairs, hin0, gcount, gstart, N);

    // Wf plane bases: g=0 -> W2_0; g=1+2l -> W1_s[l]; g=2+2l -> W2_s[l]
    #define WFG(g) (Wf + (size_t)(g) * 16384)

    // layer 0: rank1-expand + GEMM(W2_0) -> P0 (f16 + fp8 shadow)
    k_mlp0<<<gblk, 256, 0, stream>>>(hin0, W1_0, b1_0, WFG(0), b2_0,
                                     P0, P8, N);

    // layers 1..3: agg (P8 gather, P0 self -> P1) + MLP (P1 -> P0 [+P8])
    for (int l = 0; l < 3; ++l) {
        const float* b1 = b1_s + (size_t)l * HID;
        const float* b2 = b2_s + (size_t)l * HID;
        k_agg<<<abl, 256, 0, stream>>>(P8, P0, pairs, meta, P1, N);
        k_mlp<<<gblk, 256, 0, stream>>>(P1, WFG(1 + 2 * l), b1,
                                        WFG(2 + 2 * l), b2, P0, P8,
                                        (l < 2) ? 1 : 0, N);
    }

    k_head<<<G, 256, 0, stream>>>(P0, gstart, gcount, Wc, bc,
                                  (float*)d_out, G);
}